// Round 5
// baseline (229.287 us; speedup 1.0000x reference)
//
#include <hip/hip_runtime.h>

// LinearConv2D: y[b, o=g*8+n, fi, t] =
//   sum_{d<8, fr<2, w<16} x[b, g*8+d, 2*fi+fr, 4*t+w] * wt[g*8+n, d, 2*fi+fr, w]
// Shapes: x[16,64,128,256] f32, wt[64,8,128,16] f32, out[16,64,64,61] f32.
//
// R5: R1/R4 analysis shows the kernel is bound by SERIALIZED SCALAR (weight)
// LOAD latency: 8 weight rows/iter = 128 SGPRs exceeds the SGPR file, so the
// compiler issues s_load batches with lgkmcnt waits inside the loop (~240 cy
// per batch exposed). Weights don't depend on b -> each wave now processes
// TWO b values, so every s_load batch feeds 2x the FMAs (a 2-row batch is
// consumed by 128 FMAs = 256 cy > scalar latency -> hideable).
//  - (fi,g) stay pure blockIdx -> weights stay on the scalar pipe (R4 fix).
//  - x register double-buffer per b, no local arrays (no scratch, per R3).
//  - ~96 VGPRs -> __launch_bounds__(256,4); grid 1024 blocks = 16 waves/CU.

namespace {
constexpr int kB  = 16;
constexpr int kC  = 64;
constexpr int kF  = 128;
constexpr int kT  = 256;
constexpr int kG  = 8;
constexpr int kD  = 8;
constexpr int kN  = 8;
constexpr int kW  = 16;
constexpr int kKS = 4;
constexpr int kNT = 61;   // (256-16)/4 + 1
constexpr int kO  = 64;
constexpr int kFP = 64;   // (128-2)/2 + 1
constexpr int kWStride = kD * kF * kW;  // per-n weight stride (floats)
}

__device__ __forceinline__ void fma_row2(const float4& x0, const float4& x1,
                                         const float4& x2, const float4& x3,
                                         const float4& y0, const float4& y1,
                                         const float4& y2, const float4& y3,
                                         const float* __restrict__ wr,
                                         float& accx, float& accy) {
  const float4 w0 = ((const float4*)wr)[0];
  const float4 w1 = ((const float4*)wr)[1];
  const float4 w2 = ((const float4*)wr)[2];
  const float4 w3 = ((const float4*)wr)[3];
  accx = fmaf(x0.x, w0.x, accx); accy = fmaf(y0.x, w0.x, accy);
  accx = fmaf(x0.y, w0.y, accx); accy = fmaf(y0.y, w0.y, accy);
  accx = fmaf(x0.z, w0.z, accx); accy = fmaf(y0.z, w0.z, accy);
  accx = fmaf(x0.w, w0.w, accx); accy = fmaf(y0.w, w0.w, accy);
  accx = fmaf(x1.x, w1.x, accx); accy = fmaf(y1.x, w1.x, accy);
  accx = fmaf(x1.y, w1.y, accx); accy = fmaf(y1.y, w1.y, accy);
  accx = fmaf(x1.z, w1.z, accx); accy = fmaf(y1.z, w1.z, accy);
  accx = fmaf(x1.w, w1.w, accx); accy = fmaf(y1.w, w1.w, accy);
  accx = fmaf(x2.x, w2.x, accx); accy = fmaf(y2.x, w2.x, accy);
  accx = fmaf(x2.y, w2.y, accx); accy = fmaf(y2.y, w2.y, accy);
  accx = fmaf(x2.z, w2.z, accx); accy = fmaf(y2.z, w2.z, accy);
  accx = fmaf(x2.w, w2.w, accx); accy = fmaf(y2.w, w2.w, accy);
  accx = fmaf(x3.x, w3.x, accx); accy = fmaf(y3.x, w3.x, accy);
  accx = fmaf(x3.y, w3.y, accx); accy = fmaf(y3.y, w3.y, accy);
  accx = fmaf(x3.z, w3.z, accx); accy = fmaf(y3.z, w3.z, accy);
  accx = fmaf(x3.w, w3.w, accx); accy = fmaf(y3.w, w3.w, accy);
}

__global__ __launch_bounds__(256, 4)
void lc2d_kernel(const float* __restrict__ x,
                 const float* __restrict__ wt,
                 float* __restrict__ out) {
  const int lane = threadIdx.x & 63;            // t
  const int wv   = threadIdx.x >> 6;            // wave id (picks b pair)
  const int fi   = blockIdx.x;                  // 0..63  (scalar!)
  const int g    = blockIdx.y;                  // 0..7   (scalar!)
  const int b0   = blockIdx.z * 8 + wv * 2;     // 0..14 even
  const int b1   = b0 + 1;

  // Clamp inactive lanes so their (dead) loads stay in-bounds.
  const int tc   = (lane < kNT - 1) ? lane : (kNT - 1);
  const int tau0 = tc * kKS;                    // max 240; +15 = 255 in bounds

  // x[b, g*8+d, 2*fi+fr, tau]; row(it=d*2+fr) offset = d*kF*kT + fr*kT
  const float* xb0 = x + (((size_t)b0 * kC + g * kD) * kF + fi * 2) * kT + tau0;
  const float* xb1 = x + (((size_t)b1 * kC + g * kD) * kF + fi * 2) * kT + tau0;
  // wt[(g*8+n), d, 2*fi+fr, w] — depends ONLY on blockIdx -> s_load.
  const float* wbase = wt + ((size_t)(g * kN) * kD * kF + fi * 2) * (size_t)kW;

  float a00 = 0.f, a01 = 0.f, a02 = 0.f, a03 = 0.f;
  float a04 = 0.f, a05 = 0.f, a06 = 0.f, a07 = 0.f;
  float a10 = 0.f, a11 = 0.f, a12 = 0.f, a13 = 0.f;
  float a14 = 0.f, a15 = 0.f, a16 = 0.f, a17 = 0.f;

  // Prime the x register double-buffers with row 0 (d=0, fr=0).
  float4 c0 = ((const float4*)xb0)[0];
  float4 c1 = ((const float4*)xb0)[1];
  float4 c2 = ((const float4*)xb0)[2];
  float4 c3 = ((const float4*)xb0)[3];
  float4 c4 = ((const float4*)xb1)[0];
  float4 c5 = ((const float4*)xb1)[1];
  float4 c6 = ((const float4*)xb1)[2];
  float4 c7 = ((const float4*)xb1)[3];

#pragma unroll 2
  for (int it = 0; it < 16; ++it) {
    // Prefetch next x rows (it==15 reloads row 15 — harmless L1 hit).
    const int nx = (it < 15) ? it + 1 : 15;
    const size_t roff = ((size_t)(nx >> 1) * kF + (nx & 1)) * kT;
    const float* xr0 = xb0 + roff;
    const float* xr1 = xb1 + roff;
    float4 p0 = ((const float4*)xr0)[0];
    float4 p1 = ((const float4*)xr0)[1];
    float4 p2 = ((const float4*)xr0)[2];
    float4 p3 = ((const float4*)xr0)[3];
    float4 p4 = ((const float4*)xr1)[0];
    float4 p5 = ((const float4*)xr1)[1];
    float4 p6 = ((const float4*)xr1)[2];
    float4 p7 = ((const float4*)xr1)[3];

    // Weight row for (d=it>>1, fr=it&1); scalar address -> s_load.
    const float* wr = wbase + (((size_t)(it >> 1) * kF + (it & 1))) * kW;
    fma_row2(c0, c1, c2, c3, c4, c5, c6, c7, wr + 0 * kWStride, a00, a10);
    fma_row2(c0, c1, c2, c3, c4, c5, c6, c7, wr + 1 * kWStride, a01, a11);
    fma_row2(c0, c1, c2, c3, c4, c5, c6, c7, wr + 2 * kWStride, a02, a12);
    fma_row2(c0, c1, c2, c3, c4, c5, c6, c7, wr + 3 * kWStride, a03, a13);
    fma_row2(c0, c1, c2, c3, c4, c5, c6, c7, wr + 4 * kWStride, a04, a14);
    fma_row2(c0, c1, c2, c3, c4, c5, c6, c7, wr + 5 * kWStride, a05, a15);
    fma_row2(c0, c1, c2, c3, c4, c5, c6, c7, wr + 6 * kWStride, a06, a16);
    fma_row2(c0, c1, c2, c3, c4, c5, c6, c7, wr + 7 * kWStride, a07, a17);

    c0 = p0; c1 = p1; c2 = p2; c3 = p3;
    c4 = p4; c5 = p5; c6 = p6; c7 = p7;
  }

  if (lane < kNT) {
    const size_t s = (size_t)kFP * kNT;
    float* ob0 = out + (((size_t)b0 * kO + g * kN) * kFP + fi) * (size_t)kNT + lane;
    float* ob1 = out + (((size_t)b1 * kO + g * kN) * kFP + fi) * (size_t)kNT + lane;
    ob0[0 * s] = a00; ob1[0 * s] = a10;
    ob0[1 * s] = a01; ob1[1 * s] = a11;
    ob0[2 * s] = a02; ob1[2 * s] = a12;
    ob0[3 * s] = a03; ob1[3 * s] = a13;
    ob0[4 * s] = a04; ob1[4 * s] = a14;
    ob0[5 * s] = a05; ob1[5 * s] = a15;
    ob0[6 * s] = a06; ob1[6 * s] = a16;
    ob0[7 * s] = a07; ob1[7 * s] = a17;
  }
}

extern "C" void kernel_launch(void* const* d_in, const int* in_sizes, int n_in,
                              void* d_out, int out_size, void* d_ws, size_t ws_size,
                              hipStream_t stream) {
  const float* x  = (const float*)d_in[0];
  const float* wt = (const float*)d_in[1];
  float* out      = (float*)d_out;

  dim3 grid(kFP, kG, kB / 8);   // 64 x 8 x 2 = 1024 blocks of 256 threads
  lc2d_kernel<<<grid, 256, 0, stream>>>(x, wt, out);
}